// Round 2
// baseline (267.377 us; speedup 1.0000x reference)
//
#include <hip/hip_runtime.h>

#define CC 128
#define SS 4096
#define L2E 1.44269504f

typedef _Float16 f16;
typedef f16 f16x8 __attribute__((ext_vector_type(8)));
typedef __fp16 h16x2 __attribute__((ext_vector_type(2)));   // cvt_pkrtz's return type
typedef float f32x4 __attribute__((ext_vector_type(4)));

struct PArg { const float *x, *w, *b, *sc, *bb, *bm, *bv; f16* out; };

// ---------------------------------------------------------------- proj (MFMA, prep fused)
// grid (256, 3): y=p, x = b*64 + st. p=0,1 -> [B][S][C]; p=2 -> [B][C][S].
// p==0 (Q) output is pre-scaled by log2(e) so attn's softmax uses exp2 directly.
__global__ __launch_bounds__(256) void projk(PArg A0, PArg A1, PArg A2) {
    const int p = blockIdx.y;
    PArg A = (p == 0) ? A0 : ((p == 1) ? A1 : A2);
    const int bx = blockIdx.x;
    const int b  = bx >> 6;
    const int s0 = (bx & 63) * 64;
    const int tid = threadIdx.x;
    const int w = tid >> 6, lane = tid & 63;
    const int n = lane & 15, g = lane >> 4;

    __shared__ f16 Xl[64][136];                 // X^T tile [s][c]
    __shared__ f16 Wl[128][136];                // Weff [o][c], aliased as Yl
    f16* Yl = &Wl[0][0];

    // stage X: fp32 [c][s] -> f16 [s][c]
#pragma unroll
    for (int i = 0; i < 8; ++i) {
        int vi = tid + i * 256;                 // 0..2047
        int c = vi >> 4, sq = (vi & 15) * 4;
        float4 v = *(const float4*)(A.x + ((size_t)b * CC + c) * SS + s0 + sq);
        Xl[sq + 0][c] = (f16)v.x; Xl[sq + 1][c] = (f16)v.y;
        Xl[sq + 2][c] = (f16)v.z; Xl[sq + 3][c] = (f16)v.w;
    }
    // stage W (fp32 -> f16, fold inv computed directly from global)
#pragma unroll
    for (int i = 0; i < 8; ++i) {
        int vi = tid + i * 256;
        int o = vi >> 4, cq = (vi & 15) * 8;
        float iv = A.sc[o] * rsqrtf(A.bv[o] + 1e-5f);
        const float* wp = A.w + o * CC + cq;
        float4 a = *(const float4*)wp;
        float4 b4 = *(const float4*)(wp + 4);
        union { f16 h[8]; uint4 u; } pk;
        pk.h[0] = (f16)(a.x * iv);  pk.h[1] = (f16)(a.y * iv);
        pk.h[2] = (f16)(a.z * iv);  pk.h[3] = (f16)(a.w * iv);
        pk.h[4] = (f16)(b4.x * iv); pk.h[5] = (f16)(b4.y * iv);
        pk.h[6] = (f16)(b4.z * iv); pk.h[7] = (f16)(b4.w * iv);
        *(uint4*)&Wl[o][cq] = pk.u;
    }
    __syncthreads();

    if (p < 2) {
        const float qsc = (p == 0) ? L2E : 1.0f;   // pre-scale Q by log2(e)
        // D[m=o][n=s]: A=Weff, B=X. Wave w: o in [w*32, w*32+32), all 64 s.
        f32x4 acc[2][4];
#pragma unroll
        for (int mt = 0; mt < 2; ++mt)
#pragma unroll
            for (int nt = 0; nt < 4; ++nt) acc[mt][nt] = (f32x4){0.f, 0.f, 0.f, 0.f};
#pragma unroll
        for (int ks = 0; ks < 4; ++ks) {
            f16x8 af[2], bf[4];
#pragma unroll
            for (int mt = 0; mt < 2; ++mt) af[mt] = *(const f16x8*)&Wl[w * 32 + mt * 16 + n][ks * 32 + g * 8];
#pragma unroll
            for (int nt = 0; nt < 4; ++nt) bf[nt] = *(const f16x8*)&Xl[nt * 16 + n][ks * 32 + g * 8];
#pragma unroll
            for (int mt = 0; mt < 2; ++mt)
#pragma unroll
                for (int nt = 0; nt < 4; ++nt)
                    acc[mt][nt] = __builtin_amdgcn_mfma_f32_16x16x32_f16(af[mt], bf[nt], acc[mt][nt], 0, 0, 0);
        }
        __syncthreads();
#pragma unroll
        for (int mt = 0; mt < 2; ++mt) {
            float ebr[4];
#pragma unroll
            for (int r = 0; r < 4; ++r) {
                int o = w * 32 + mt * 16 + g * 4 + r;
                float iv = A.sc[o] * rsqrtf(A.bv[o] + 1e-5f);
                ebr[r] = (A.b[o] - A.bm[o]) * iv + A.bb[o];
            }
#pragma unroll
            for (int nt = 0; nt < 4; ++nt) {
                union { f16 h[4]; uint2 u; } pk;
#pragma unroll
                for (int r = 0; r < 4; ++r) {
                    float y = acc[mt][nt][r] + ebr[r];
                    y = (y > 0.f) ? y : (__expf(y) - 1.f);
                    pk.h[r] = (f16)(y * qsc);
                }
                *(uint2*)&Yl[(nt * 16 + n) * 136 + w * 32 + mt * 16 + g * 4] = pk.u;
            }
        }
        __syncthreads();
#pragma unroll
        for (int i = 0; i < 4; ++i) {
            int vi = tid + i * 256;
            int s = vi >> 4, cl = (vi & 15) * 8;
            *(uint4*)&A.out[((size_t)b * SS + s0 + s) * CC + cl] = *(const uint4*)&Yl[s * 136 + cl];
        }
    } else {
        // D[m=s][n=o]: A=X, B=Weff. Wave w: s in [w*16, w*16+16), all 128 o.
        f32x4 acc[8];
#pragma unroll
        for (int nt = 0; nt < 8; ++nt) acc[nt] = (f32x4){0.f, 0.f, 0.f, 0.f};
#pragma unroll
        for (int ks = 0; ks < 4; ++ks) {
            f16x8 af = *(const f16x8*)&Xl[w * 16 + n][ks * 32 + g * 8];
#pragma unroll
            for (int nt = 0; nt < 8; ++nt) {
                f16x8 bf = *(const f16x8*)&Wl[nt * 16 + n][ks * 32 + g * 8];
                acc[nt] = __builtin_amdgcn_mfma_f32_16x16x32_f16(af, bf, acc[nt], 0, 0, 0);
            }
        }
        __syncthreads();
#pragma unroll
        for (int nt = 0; nt < 8; ++nt) {
            int o = nt * 16 + n;
            float iv = A.sc[o] * rsqrtf(A.bv[o] + 1e-5f);
            float ebc = (A.b[o] - A.bm[o]) * iv + A.bb[o];
            union { f16 h[4]; uint2 u; } pk;
#pragma unroll
            for (int r = 0; r < 4; ++r) {
                float y = acc[nt][r] + ebc;
                y = (y > 0.f) ? y : (__expf(y) - 1.f);
                pk.h[r] = (f16)y;
            }
            *(uint2*)&Yl[(nt * 16 + n) * 136 + w * 16 + g * 4] = pk.u;   // Yl[o][s]
        }
        __syncthreads();
#pragma unroll
        for (int i = 0; i < 4; ++i) {
            int vi = tid + i * 256;
            int o = vi >> 3, sl = (vi & 7) * 8;
            *(uint4*)&A.out[((size_t)b * CC + o) * SS + s0 + sl] = *(const uint4*)&Yl[o * 136 + sl];
        }
    }
}

// ---------------------------------------------------------------- attention
// Double-buffered LDS, ONE barrier per 32-key step. Loads issued right after the
// barrier, consumed by ds_write only after phase A (latency hidden; no register
// live-range across a barrier -> no scratch spill). XCD swizzle kept.
// NOTE: R15/R16 added a mid-loop divergent branch (lazy rescale) — it broke the
// compiler's load scheduling (FETCH/WRITE 2x, dur +56%). Keep this loop branch-free.
//
// LDS arena = 40960 B exactly -> 4 blocks/CU; grid 1024 = 256 CU * 4 all-resident
// (no straggler round). Layout (all conflict-free, bank math in journal):
//   [    0,16384) K dbuf: 2 x [32 k][128 c] f16, 16B-granule XOR swizzle c16^=(row&7)
//   [16384,32768) V dbuf: 2 x [128 c][32 k] f16, linear (row stride 64 B)
//   [32768,40960) P: 4 waves x [32 q][32 k] f16, linear, wave-private
__device__ __forceinline__ void* kg(char* base, int row, int c16) {
    return base + row * 256 + (((c16) ^ (row & 7)) << 4);
}

__global__ __launch_bounds__(256, 4) void attnk(
    const f16* __restrict__ Qt, const f16* __restrict__ Kt, const f16* __restrict__ Vt,
    f16* __restrict__ Op, float* __restrict__ Ml)
{
    const int tid = threadIdx.x;
    const int bx = blockIdx.x;
    const int kh = bx & 7;
    const int b  = (bx >> 3) & 3;
    const int qt = bx >> 5;
    const int q0 = qt * 128;
    const int kbeg = kh * 512;

    __shared__ __align__(16) char arena[40960];
    const int w = tid >> 6, lane = tid & 63;
    const int n = lane & 15, g = lane >> 4;
    char* Pb = arena + 32768 + w * 2048;        // wave-private P [32 q][32 k]

    // Q B-frags from global (Qt pre-scaled by log2(e) in projk)
    f16x8 qf[2][4];
    {
        const f16* Qb = Qt + ((size_t)b * SS + q0 + w * 32) * CC;
#pragma unroll
        for (int qt2 = 0; qt2 < 2; ++qt2)
#pragma unroll
            for (int ks = 0; ks < 4; ++ks)
                qf[qt2][ks] = *(const f16x8*)&Qb[(qt2 * 16 + n) * CC + ks * 32 + g * 8];
    }

    f32x4 oacc[8][2];                            // O^T: c = mtc*16+g*4+r, q = w*32+qt2*16+n
#pragma unroll
    for (int mtc = 0; mtc < 8; ++mtc)
#pragma unroll
        for (int qt2 = 0; qt2 < 2; ++qt2) oacc[mtc][qt2] = (f32x4){0.f, 0.f, 0.f, 0.f};
    float mreg[2] = {-1e30f, -1e30f}, lsum[2] = {0.f, 0.f};

    // staging coords for this thread (2 x 16B each for K and V; second row = +16 / +64)
    const int rk0 = tid >> 4, c16k = tid & 15;   // K: row, col-granule (8 f16)
    const int rv0 = tid >> 2, cvg  = tid & 3;    // V: row (channel), key-granule

    // prologue: stage tile 0 into buffer 0
    {
        char* Kb = arena;
        char* Vb = arena + 16384;
        const f16* Ksrc = Kt + ((size_t)b * SS + kbeg) * CC;
        const f16* Vsrc = Vt + (size_t)b * CC * SS + kbeg;
        *(uint4*)kg(Kb, rk0,      c16k) = *(const uint4*)&Ksrc[rk0 * CC + c16k * 8];
        *(uint4*)kg(Kb, rk0 + 16, c16k) = *(const uint4*)&Ksrc[(rk0 + 16) * CC + c16k * 8];
        *(uint4*)(Vb + rv0 * 64 + cvg * 16)        = *(const uint4*)&Vsrc[(size_t)rv0 * SS + cvg * 8];
        *(uint4*)(Vb + (rv0 + 64) * 64 + cvg * 16) = *(const uint4*)&Vsrc[(size_t)(rv0 + 64) * SS + cvg * 8];
    }

    for (int kt = 0; kt < 16; ++kt) {
        const int cur = kt & 1;
        char* Kb = arena + cur * 8192;
        char* Vb = arena + 16384 + cur * 8192;
        char* Kn = arena + (1 - cur) * 8192;
        char* Vn = arena + 16384 + (1 - cur) * 8192;

        __syncthreads();                        // buf[cur] writes done; buf[1-cur] reads done

        // issue next-tile loads (land during phase A)
        uint4 nk0, nk1, nv0, nv1;
        if (kt < 15) {
            const int k1 = kbeg + (kt + 1) * 32;
            const f16* Ksrc = Kt + ((size_t)b * SS + k1) * CC;
            const f16* Vsrc = Vt + (size_t)b * CC * SS + k1;
            nk0 = *(const uint4*)&Ksrc[rk0 * CC + c16k * 8];
            nk1 = *(const uint4*)&Ksrc[(rk0 + 16) * CC + c16k * 8];
            nv0 = *(const uint4*)&Vsrc[(size_t)rv0 * SS + cvg * 8];
            nv1 = *(const uint4*)&Vsrc[(size_t)(rv0 + 64) * SS + cvg * 8];
        }

        // phase A: S^T[key][q] = K.Q^T  (A=K, B=Q). key = kt2*16+g*4+r, q = w*32+qt2*16+n
        f32x4 sacc[2][2];
#pragma unroll
        for (int kt2 = 0; kt2 < 2; ++kt2)
#pragma unroll
            for (int qt2 = 0; qt2 < 2; ++qt2) sacc[kt2][qt2] = (f32x4){0.f, 0.f, 0.f, 0.f};
        __builtin_amdgcn_s_setprio(1);
#pragma unroll
        for (int ks = 0; ks < 4; ++ks) {
            f16x8 kf[2];
            kf[0] = *(const f16x8*)kg(Kb, n,      ks * 4 + g);
            kf[1] = *(const f16x8*)kg(Kb, 16 + n, ks * 4 + g);
#pragma unroll
            for (int kt2 = 0; kt2 < 2; ++kt2)
#pragma unroll
                for (int qt2 = 0; qt2 < 2; ++qt2)
                    sacc[kt2][qt2] = __builtin_amdgcn_mfma_f32_16x16x32_f16(kf[kt2], qf[qt2][ks], sacc[kt2][qt2], 0, 0, 0);
        }
        __builtin_amdgcn_s_setprio(0);

        // stage next tile into the other buffer (no one reads it until next barrier)
        if (kt < 15) {
            *(uint4*)kg(Kn, rk0,      c16k) = nk0;
            *(uint4*)kg(Kn, rk0 + 16, c16k) = nk1;
            *(uint4*)(Vn + rv0 * 64 + cvg * 16)        = nv0;
            *(uint4*)(Vn + (rv0 + 64) * 64 + cvg * 16) = nv1;
        }

        // online softmax per q-column. sacc is already in log2-domain (Q pre-scaled).
        float al[2];
#pragma unroll
        for (int qt2 = 0; qt2 < 2; ++qt2) {
            float v = fmaxf(fmaxf(fmaxf(sacc[0][qt2][0], sacc[0][qt2][1]),
                                  fmaxf(sacc[0][qt2][2], sacc[0][qt2][3])),
                            fmaxf(fmaxf(sacc[1][qt2][0], sacc[1][qt2][1]),
                                  fmaxf(sacc[1][qt2][2], sacc[1][qt2][3])));
            v = fmaxf(v, __shfl_xor(v, 16));
            v = fmaxf(v, __shfl_xor(v, 32));
            float mn = fmaxf(mreg[qt2], v);
            al[qt2] = exp2f(mreg[qt2] - mn);
            mreg[qt2] = mn;
            float rs = 0.f;
#pragma unroll
            for (int kt2 = 0; kt2 < 2; ++kt2) {
                float p0 = exp2f(sacc[kt2][qt2][0] - mn);
                float p1 = exp2f(sacc[kt2][qt2][1] - mn);
                float p2 = exp2f(sacc[kt2][qt2][2] - mn);
                float p3 = exp2f(sacc[kt2][qt2][3] - mn);
                rs += (p0 + p1) + (p2 + p3);
                union { h16x2 h[2]; uint2 u; } pk;
                pk.h[0] = __builtin_amdgcn_cvt_pkrtz(p0, p1);
                pk.h[1] = __builtin_amdgcn_cvt_pkrtz(p2, p3);
                *(uint2*)(Pb + (qt2 * 16 + n) * 64 + kt2 * 32 + g * 8) = pk.u;
            }
            lsum[qt2] = lsum[qt2] * al[qt2] + rs;   // per-lane partial; reduced at end
        }
#pragma unroll
        for (int mtc = 0; mtc < 8; ++mtc)
#pragma unroll
            for (int qt2 = 0; qt2 < 2; ++qt2)
                oacc[mtc][qt2] *= al[qt2];

        // phase B: O^T[c][q] += V.P^T  (A=V[c][key], B=P[q][key]; one K=32 chunk)
        {
            f16x8 pf[2];
            pf[0] = *(const f16x8*)(Pb + n * 64 + g * 16);
            pf[1] = *(const f16x8*)(Pb + (16 + n) * 64 + g * 16);
            __builtin_amdgcn_s_setprio(1);
#pragma unroll
            for (int mtc = 0; mtc < 8; ++mtc) {
                f16x8 vf = *(const f16x8*)(Vb + (mtc * 16 + n) * 64 + g * 16);
#pragma unroll
                for (int qt2 = 0; qt2 < 2; ++qt2)
                    oacc[mtc][qt2] = __builtin_amdgcn_mfma_f32_16x16x32_f16(vf, pf[qt2], oacc[mtc][qt2], 0, 0, 0);
            }
            __builtin_amdgcn_s_setprio(0);
        }
    }

    // final l reduction over g-lanes
    float lreg[2];
#pragma unroll
    for (int qt2 = 0; qt2 < 2; ++qt2) {
        float s = lsum[qt2];
        s += __shfl_xor(s, 16);
        s += __shfl_xor(s, 32);
        lreg[qt2] = s;
    }

    const int pidx = (b * 32 + qt) * 8 + kh;
    if (g == 0) {
        float* MlW = Ml + (size_t)pidx * 256;
#pragma unroll
        for (int qt2 = 0; qt2 < 2; ++qt2) {
            int q = w * 32 + qt2 * 16 + n;
            MlW[q]       = mreg[qt2];           // log2-domain max (mrgk matches)
            MlW[128 + q] = lreg[qt2];
        }
    }

    // epilogue: transpose O^T frags through LDS (reuse arena), coalesced store
    __syncthreads();                            // all phase-B reads done
    f16 (*S2)[136] = (f16(*)[136])arena;        // [128 c][128 q] = 34816 B (fits arena)
#pragma unroll
    for (int mtc = 0; mtc < 8; ++mtc)
#pragma unroll
        for (int qt2 = 0; qt2 < 2; ++qt2)
#pragma unroll
            for (int r = 0; r < 4; ++r)
                S2[mtc * 16 + g * 4 + r][w * 32 + qt2 * 16 + n] = (f16)oacc[mtc][qt2][r];
    __syncthreads();
    f16* OpW = Op + (size_t)pidx * 16384;
#pragma unroll
    for (int i = 0; i < 8; ++i) {
        int vi = tid + i * 256;                 // 0..2047
        int c = vi >> 4, qq = (vi & 15) * 8;
        *(uint4*)&OpW[c * 128 + qq] = *(const uint4*)&S2[c][qq];
    }
}

// ---------------------------------------------------------------- merge (8 partials)
// Ml maxes are stored in log2-domain (Q pre-scaled by log2 e) -> exp2 without L2E.
__global__ __launch_bounds__(256) void mrgk(
    const f16* __restrict__ Op, const float* __restrict__ Ml,
    const float* __restrict__ xv, const float* __restrict__ gp, const float* __restrict__ bp,
    float* __restrict__ out)
{
    const int bx = blockIdx.x;                 // (b*32+qt)*4 + cg
    const int cg = bx & 3, bqt = bx >> 2;
    const int b = bqt >> 5, qt = bqt & 31;
    const int tid = threadIdx.x;
    const int q = tid & 127, hf = tid >> 7;

    const float* ml = Ml + (size_t)bqt * 8 * 256;
    float m = -1e30f;
#pragma unroll
    for (int k2 = 0; k2 < 8; ++k2) m = fmaxf(m, ml[k2 * 256 + q]);
    float wt[8], tot = 0.f;
#pragma unroll
    for (int k2 = 0; k2 < 8; ++k2) {
        wt[k2] = exp2f(ml[k2 * 256 + q] - m);
        tot += wt[k2] * ml[k2 * 256 + 128 + q];
    }
    float inv = 1.f / tot;
    float gm = gp[0], bb = bp[0];

    const f16* O = Op + (size_t)bqt * 8 * 16384;
#pragma unroll 2
    for (int i = 0; i < 16; ++i) {
        int c = cg * 32 + hf * 16 + i;
        float o = 0.f;
#pragma unroll
        for (int k2 = 0; k2 < 8; ++k2) o += wt[k2] * (float)O[k2 * 16384 + c * 128 + q];
        o *= inv;
        size_t idx = ((size_t)(b * CC + c)) * SS + qt * 128 + q;
        out[idx] = gm * o + bb * xv[idx];
    }
}

// ---------------------------------------------------------------- launcher
extern "C" void kernel_launch(void* const* d_in, const int* in_sizes, int n_in,
                              void* d_out, int out_size, void* d_ws, size_t ws_size,
                              hipStream_t stream) {
    (void)in_sizes; (void)n_in; (void)out_size; (void)ws_size;

    const size_t TEN = (size_t)4 * SS * CC;          // 2,097,152
    f16* Qt = (f16*)d_ws;                            // 4 MB
    f16* Kt = Qt + TEN;                              // 4 MB
    f16* Vt = Kt + TEN;                              // 4 MB (channel-major)
    f16* Op = Vt + TEN;                              // 1024*16384 f16 = 32 MB
    float* Ml = (float*)(Op + (size_t)1024 * 16384); // 1 MB

    PArg aq = { (const float*)d_in[0], (const float*)d_in[3],  (const float*)d_in[4],
                (const float*)d_in[5], (const float*)d_in[6],  (const float*)d_in[7],
                (const float*)d_in[8],  Qt };
    PArg ak = { (const float*)d_in[1], (const float*)d_in[9],  (const float*)d_in[10],
                (const float*)d_in[11], (const float*)d_in[12], (const float*)d_in[13],
                (const float*)d_in[14], Kt };
    PArg av = { (const float*)d_in[2], (const float*)d_in[15], (const float*)d_in[16],
                (const float*)d_in[17], (const float*)d_in[18], (const float*)d_in[19],
                (const float*)d_in[20], Vt };

    hipLaunchKernelGGL(projk, dim3(256, 3), dim3(256), 0, stream, aq, ak, av);
    hipLaunchKernelGGL(attnk, dim3(1024), dim3(256), 0, stream, Qt, Kt, Vt, Op, Ml);
    hipLaunchKernelGGL(mrgk, dim3(512), dim3(256), 0, stream,
                       Op, Ml, (const float*)d_in[2], (const float*)d_in[21],
                       (const float*)d_in[22], (float*)d_out);
}

// Round 3
// 183.444 us; speedup vs baseline: 1.4575x; 1.4575x over previous
//
#include <hip/hip_runtime.h>

#define CC 128
#define SS 4096
#define L2E 1.44269504f

typedef _Float16 f16;
typedef f16 f16x8 __attribute__((ext_vector_type(8)));
typedef __fp16 h16x2 __attribute__((ext_vector_type(2)));   // cvt_pkrtz's return type
typedef float f32x4 __attribute__((ext_vector_type(4)));

struct PArg { const float *x, *w, *b, *sc, *bb, *bm, *bv; f16* out; };

// ---------------------------------------------------------------- proj (MFMA, prep fused)
// grid (256, 3): y=p, x = b*64 + st. p=0,1 -> [B][S][C]; p=2 -> [B][C][S].
// p==0 (Q) output is pre-scaled by log2(e) so attn's softmax uses exp2 directly.
__global__ __launch_bounds__(256) void projk(PArg A0, PArg A1, PArg A2) {
    const int p = blockIdx.y;
    PArg A = (p == 0) ? A0 : ((p == 1) ? A1 : A2);
    const int bx = blockIdx.x;
    const int b  = bx >> 6;
    const int s0 = (bx & 63) * 64;
    const int tid = threadIdx.x;
    const int w = tid >> 6, lane = tid & 63;
    const int n = lane & 15, g = lane >> 4;

    __shared__ f16 Xl[64][136];                 // X^T tile [s][c]
    __shared__ f16 Wl[128][136];                // Weff [o][c], aliased as Yl
    f16* Yl = &Wl[0][0];

    // stage X: fp32 [c][s] -> f16 [s][c]
#pragma unroll
    for (int i = 0; i < 8; ++i) {
        int vi = tid + i * 256;                 // 0..2047
        int c = vi >> 4, sq = (vi & 15) * 4;
        float4 v = *(const float4*)(A.x + ((size_t)b * CC + c) * SS + s0 + sq);
        Xl[sq + 0][c] = (f16)v.x; Xl[sq + 1][c] = (f16)v.y;
        Xl[sq + 2][c] = (f16)v.z; Xl[sq + 3][c] = (f16)v.w;
    }
    // stage W (fp32 -> f16, fold inv computed directly from global)
#pragma unroll
    for (int i = 0; i < 8; ++i) {
        int vi = tid + i * 256;
        int o = vi >> 4, cq = (vi & 15) * 8;
        float iv = A.sc[o] * rsqrtf(A.bv[o] + 1e-5f);
        const float* wp = A.w + o * CC + cq;
        float4 a = *(const float4*)wp;
        float4 b4 = *(const float4*)(wp + 4);
        union { f16 h[8]; uint4 u; } pk;
        pk.h[0] = (f16)(a.x * iv);  pk.h[1] = (f16)(a.y * iv);
        pk.h[2] = (f16)(a.z * iv);  pk.h[3] = (f16)(a.w * iv);
        pk.h[4] = (f16)(b4.x * iv); pk.h[5] = (f16)(b4.y * iv);
        pk.h[6] = (f16)(b4.z * iv); pk.h[7] = (f16)(b4.w * iv);
        *(uint4*)&Wl[o][cq] = pk.u;
    }
    __syncthreads();

    if (p < 2) {
        const float qsc = (p == 0) ? L2E : 1.0f;   // pre-scale Q by log2(e)
        // D[m=o][n=s]: A=Weff, B=X. Wave w: o in [w*32, w*32+32), all 64 s.
        f32x4 acc[2][4];
#pragma unroll
        for (int mt = 0; mt < 2; ++mt)
#pragma unroll
            for (int nt = 0; nt < 4; ++nt) acc[mt][nt] = (f32x4){0.f, 0.f, 0.f, 0.f};
#pragma unroll
        for (int ks = 0; ks < 4; ++ks) {
            f16x8 af[2], bf[4];
#pragma unroll
            for (int mt = 0; mt < 2; ++mt) af[mt] = *(const f16x8*)&Wl[w * 32 + mt * 16 + n][ks * 32 + g * 8];
#pragma unroll
            for (int nt = 0; nt < 4; ++nt) bf[nt] = *(const f16x8*)&Xl[nt * 16 + n][ks * 32 + g * 8];
#pragma unroll
            for (int mt = 0; mt < 2; ++mt)
#pragma unroll
                for (int nt = 0; nt < 4; ++nt)
                    acc[mt][nt] = __builtin_amdgcn_mfma_f32_16x16x32_f16(af[mt], bf[nt], acc[mt][nt], 0, 0, 0);
        }
        __syncthreads();
#pragma unroll
        for (int mt = 0; mt < 2; ++mt) {
            float ebr[4];
#pragma unroll
            for (int r = 0; r < 4; ++r) {
                int o = w * 32 + mt * 16 + g * 4 + r;
                float iv = A.sc[o] * rsqrtf(A.bv[o] + 1e-5f);
                ebr[r] = (A.b[o] - A.bm[o]) * iv + A.bb[o];
            }
#pragma unroll
            for (int nt = 0; nt < 4; ++nt) {
                union { f16 h[4]; uint2 u; } pk;
#pragma unroll
                for (int r = 0; r < 4; ++r) {
                    float y = acc[mt][nt][r] + ebr[r];
                    y = (y > 0.f) ? y : (__expf(y) - 1.f);
                    pk.h[r] = (f16)(y * qsc);
                }
                *(uint2*)&Yl[(nt * 16 + n) * 136 + w * 32 + mt * 16 + g * 4] = pk.u;
            }
        }
        __syncthreads();
#pragma unroll
        for (int i = 0; i < 4; ++i) {
            int vi = tid + i * 256;
            int s = vi >> 4, cl = (vi & 15) * 8;
            *(uint4*)&A.out[((size_t)b * SS + s0 + s) * CC + cl] = *(const uint4*)&Yl[s * 136 + cl];
        }
    } else {
        // D[m=s][n=o]: A=X, B=Weff. Wave w: s in [w*16, w*16+16), all 128 o.
        f32x4 acc[8];
#pragma unroll
        for (int nt = 0; nt < 8; ++nt) acc[nt] = (f32x4){0.f, 0.f, 0.f, 0.f};
#pragma unroll
        for (int ks = 0; ks < 4; ++ks) {
            f16x8 af = *(const f16x8*)&Xl[w * 16 + n][ks * 32 + g * 8];
#pragma unroll
            for (int nt = 0; nt < 8; ++nt) {
                f16x8 bf = *(const f16x8*)&Wl[nt * 16 + n][ks * 32 + g * 8];
                acc[nt] = __builtin_amdgcn_mfma_f32_16x16x32_f16(af, bf, acc[nt], 0, 0, 0);
            }
        }
        __syncthreads();
#pragma unroll
        for (int nt = 0; nt < 8; ++nt) {
            int o = nt * 16 + n;
            float iv = A.sc[o] * rsqrtf(A.bv[o] + 1e-5f);
            float ebc = (A.b[o] - A.bm[o]) * iv + A.bb[o];
            union { f16 h[4]; uint2 u; } pk;
#pragma unroll
            for (int r = 0; r < 4; ++r) {
                float y = acc[nt][r] + ebc;
                y = (y > 0.f) ? y : (__expf(y) - 1.f);
                pk.h[r] = (f16)y;
            }
            *(uint2*)&Yl[(nt * 16 + n) * 136 + w * 16 + g * 4] = pk.u;   // Yl[o][s]
        }
        __syncthreads();
#pragma unroll
        for (int i = 0; i < 4; ++i) {
            int vi = tid + i * 256;
            int o = vi >> 3, sl = (vi & 7) * 8;
            *(uint4*)&A.out[((size_t)b * CC + o) * SS + s0 + sl] = *(const uint4*)&Yl[o * 136 + sl];
        }
    }
}

// ---------------------------------------------------------------- attention
// q-tile 64 (wave = 16 q x 128 c): halves per-wave registers (oacc 32, qf 16)
// so 4 waves/SIMD fits WITHOUT spilling (R2 post-mortem: forcing 4 at the old
// 32q tile needed 148 regs in a 128 cap -> 20x FETCH from scratch spill).
// Grid 2048 = 2 exact rounds at 4 blocks/CU -> no straggler tail.
// Double-buffered LDS, ONE barrier per 32-key step; loop branch-free (R15/R16).
//
// LDS arena = 37888:
//   [    0,16384) K dbuf: 2 x [32 k][128 c] f16, 16B-granule XOR swizzle (2-way max)
//   [16384,32768) V dbuf: 2 x [128 c][32 k] f16, granule swizzle u^((u>>3)&7) (2-way max)
//   [32768,37888) P: 4 waves x [16 q][40 k] f16 (80 B rows, 2-way max)
__device__ __forceinline__ void* kg(char* base, int row, int c16) {
    return base + row * 256 + (((c16) ^ (row & 7)) << 4);
}
__device__ __forceinline__ int vswz(int u) {        // 16B-granule index swizzle, bijective
    return (u & ~7) | ((u ^ (u >> 3)) & 7);
}

__global__ __launch_bounds__(256, 4) void attnk(
    const f16* __restrict__ Qt, const f16* __restrict__ Kt, const f16* __restrict__ Vt,
    f16* __restrict__ Op, float* __restrict__ Ml)
{
    const int tid = threadIdx.x;
    const int bx = blockIdx.x;
    const int kh = bx & 7;                      // low bits -> XCD-local K/V chunk
    const int b  = (bx >> 3) & 3;
    const int qt = bx >> 5;                     // 0..63
    const int q0 = qt * 64;
    const int kbeg = kh * 512;

    __shared__ __align__(16) char arena[37888];
    const int w = tid >> 6, lane = tid & 63;
    const int n = lane & 15, g = lane >> 4;
    char* Pb = arena + 32768 + w * 1280;        // wave-private P [16 q][40 f16]

    // Q frags: wave owns q in [q0+w*16, +16). Qt pre-scaled by log2(e).
    f16x8 qf[4];
    {
        const f16* Qb = Qt + ((size_t)b * SS + q0 + w * 16) * CC;
#pragma unroll
        for (int ks = 0; ks < 4; ++ks)
            qf[ks] = *(const f16x8*)&Qb[n * CC + ks * 32 + g * 8];
    }

    f32x4 oacc[8];                              // O^T: c = mtc*16+g*4+r, q = q0+w*16+n
#pragma unroll
    for (int mtc = 0; mtc < 8; ++mtc) oacc[mtc] = (f32x4){0.f, 0.f, 0.f, 0.f};
    float mreg = -1e30f, lsum = 0.f;

    // staging coords (2 x 16B each for K and V)
    const int rk0 = tid >> 4, c16k = tid & 15;  // K: row, col-granule
    const int rv0 = tid >> 2, cvg  = tid & 3;   // V: row (channel), key-granule
    const int vw0 = vswz(tid) << 4, vw1 = vswz(tid + 256) << 4;  // V LDS byte offs

    // prologue: stage tile 0 into buffer 0
    {
        char* Kb = arena;
        char* Vb = arena + 16384;
        const f16* Ksrc = Kt + ((size_t)b * SS + kbeg) * CC;
        const f16* Vsrc = Vt + (size_t)b * CC * SS + kbeg;
        *(uint4*)kg(Kb, rk0,      c16k) = *(const uint4*)&Ksrc[rk0 * CC + c16k * 8];
        *(uint4*)kg(Kb, rk0 + 16, c16k) = *(const uint4*)&Ksrc[(rk0 + 16) * CC + c16k * 8];
        *(uint4*)(Vb + vw0) = *(const uint4*)&Vsrc[(size_t)rv0 * SS + cvg * 8];
        *(uint4*)(Vb + vw1) = *(const uint4*)&Vsrc[(size_t)(rv0 + 64) * SS + cvg * 8];
    }

    for (int kt = 0; kt < 16; ++kt) {
        const int cur = kt & 1;
        char* Kb = arena + cur * 8192;
        char* Vb = arena + 16384 + cur * 8192;
        char* Kn = arena + (1 - cur) * 8192;
        char* Vn = arena + 16384 + (1 - cur) * 8192;

        __syncthreads();                        // buf[cur] writes done; buf[1-cur] reads done

        // issue next-tile loads (land during phase A)
        uint4 nk0, nk1, nv0, nv1;
        if (kt < 15) {
            const int k1 = kbeg + (kt + 1) * 32;
            const f16* Ksrc = Kt + ((size_t)b * SS + k1) * CC;
            const f16* Vsrc = Vt + (size_t)b * CC * SS + k1;
            nk0 = *(const uint4*)&Ksrc[rk0 * CC + c16k * 8];
            nk1 = *(const uint4*)&Ksrc[(rk0 + 16) * CC + c16k * 8];
            nv0 = *(const uint4*)&Vsrc[(size_t)rv0 * SS + cvg * 8];
            nv1 = *(const uint4*)&Vsrc[(size_t)(rv0 + 64) * SS + cvg * 8];
        }

        // phase A: S^T[key][q] = K.Q^T. key = kt2*16+g*4+r, q = q0+w*16+n
        f32x4 sacc[2];
        sacc[0] = (f32x4){0.f, 0.f, 0.f, 0.f};
        sacc[1] = (f32x4){0.f, 0.f, 0.f, 0.f};
        __builtin_amdgcn_s_setprio(1);
#pragma unroll
        for (int ks = 0; ks < 4; ++ks) {
            f16x8 kf0 = *(const f16x8*)kg(Kb, n,      ks * 4 + g);
            f16x8 kf1 = *(const f16x8*)kg(Kb, 16 + n, ks * 4 + g);
            sacc[0] = __builtin_amdgcn_mfma_f32_16x16x32_f16(kf0, qf[ks], sacc[0], 0, 0, 0);
            sacc[1] = __builtin_amdgcn_mfma_f32_16x16x32_f16(kf1, qf[ks], sacc[1], 0, 0, 0);
        }
        __builtin_amdgcn_s_setprio(0);

        // stage next tile into the other buffer (no one reads it until next barrier)
        if (kt < 15) {
            *(uint4*)kg(Kn, rk0,      c16k) = nk0;
            *(uint4*)kg(Kn, rk0 + 16, c16k) = nk1;
            *(uint4*)(Vn + vw0) = nv0;
            *(uint4*)(Vn + vw1) = nv1;
        }

        // online softmax (log2 domain). Lane holds 8 keys of column q=q0+w*16+n.
        {
            float v = fmaxf(fmaxf(fmaxf(sacc[0][0], sacc[0][1]), fmaxf(sacc[0][2], sacc[0][3])),
                            fmaxf(fmaxf(sacc[1][0], sacc[1][1]), fmaxf(sacc[1][2], sacc[1][3])));
            v = fmaxf(v, __shfl_xor(v, 16));
            v = fmaxf(v, __shfl_xor(v, 32));
            float mn = fmaxf(mreg, v);
            float al = exp2f(mreg - mn);
            mreg = mn;
            float rs = 0.f;
#pragma unroll
            for (int kt2 = 0; kt2 < 2; ++kt2) {
                float p0 = exp2f(sacc[kt2][0] - mn);
                float p1 = exp2f(sacc[kt2][1] - mn);
                float p2 = exp2f(sacc[kt2][2] - mn);
                float p3 = exp2f(sacc[kt2][3] - mn);
                rs += (p0 + p1) + (p2 + p3);
                union { h16x2 h[2]; uint2 u; } pk;
                pk.h[0] = __builtin_amdgcn_cvt_pkrtz(p0, p1);
                pk.h[1] = __builtin_amdgcn_cvt_pkrtz(p2, p3);
                *(uint2*)(Pb + n * 80 + kt2 * 32 + g * 8) = pk.u;
            }
            lsum = lsum * al + rs;              // per-lane partial; reduced at end
#pragma unroll
            for (int mtc = 0; mtc < 8; ++mtc) oacc[mtc] *= al;
        }

        // phase B: O^T[c][q] += V.P^T  (A=V[c][key], B=P[q][key]; one K=32 chunk)
        {
            f16x8 pf = *(const f16x8*)(Pb + n * 80 + g * 16);
            __builtin_amdgcn_s_setprio(1);
#pragma unroll
            for (int mtc = 0; mtc < 8; ++mtc) {
                f16x8 vf = *(const f16x8*)(Vb + (vswz((mtc * 16 + n) * 4 + g) << 4));
                oacc[mtc] = __builtin_amdgcn_mfma_f32_16x16x32_f16(vf, pf, oacc[mtc], 0, 0, 0);
            }
            __builtin_amdgcn_s_setprio(0);
        }
    }

    // final l reduction over g-lanes
    float lreg;
    {
        float s = lsum;
        s += __shfl_xor(s, 16);
        s += __shfl_xor(s, 32);
        lreg = s;
    }

    const int pidx = (b * 64 + qt) * 8 + kh;
    if (g == 0) {
        float* MlW = Ml + (size_t)pidx * 128;
        MlW[w * 16 + n]      = mreg;            // log2-domain max (mrgk matches)
        MlW[64 + w * 16 + n] = lreg;
    }

    // epilogue: transpose O^T frags through LDS (reuse arena), coalesced store
    __syncthreads();                            // all phase-B reads done
    f16 (*S2)[72] = (f16(*)[72])arena;          // [128 c][64 q] padded = 18432 B
#pragma unroll
    for (int mtc = 0; mtc < 8; ++mtc)
#pragma unroll
        for (int r = 0; r < 4; ++r)
            S2[mtc * 16 + g * 4 + r][w * 16 + n] = (f16)oacc[mtc][r];
    __syncthreads();
    f16* OpW = Op + (size_t)pidx * 8192;        // [128 c][64 q]
#pragma unroll
    for (int i = 0; i < 4; ++i) {
        int vi = tid + i * 256;                 // 0..1023
        int c = vi >> 3, qq = (vi & 7) * 8;
        *(uint4*)&OpW[c * 64 + qq] = *(const uint4*)&S2[c][qq];
    }
}

// ---------------------------------------------------------------- merge (8 partials)
// Ml maxes are stored in log2-domain (Q pre-scaled by log2 e) -> exp2 without L2E.
__global__ __launch_bounds__(256) void mrgk(
    const f16* __restrict__ Op, const float* __restrict__ Ml,
    const float* __restrict__ xv, const float* __restrict__ gp, const float* __restrict__ bp,
    float* __restrict__ out)
{
    const int bx = blockIdx.x;                 // bqt*4 + cg
    const int cg = bx & 3, bqt = bx >> 2;      // bqt = b*64 + qt, 0..255
    const int b = bqt >> 6, qt = bqt & 63;
    const int tid = threadIdx.x;
    const int q = tid & 63, hf = tid >> 6;     // hf 0..3

    const float* ml = Ml + (size_t)bqt * 8 * 128;
    float m = -1e30f;
#pragma unroll
    for (int k2 = 0; k2 < 8; ++k2) m = fmaxf(m, ml[k2 * 128 + q]);
    float wt[8], tot = 0.f;
#pragma unroll
    for (int k2 = 0; k2 < 8; ++k2) {
        wt[k2] = exp2f(ml[k2 * 128 + q] - m);
        tot += wt[k2] * ml[k2 * 128 + 64 + q];
    }
    float inv = 1.f / tot;
    float gm = gp[0], bb = bp[0];

    const f16* O = Op + (size_t)bqt * 8 * 8192;
#pragma unroll 2
    for (int i = 0; i < 8; ++i) {
        int c = cg * 32 + hf * 8 + i;
        float o = 0.f;
#pragma unroll
        for (int k2 = 0; k2 < 8; ++k2) o += wt[k2] * (float)O[k2 * 8192 + c * 64 + q];
        o *= inv;
        size_t idx = ((size_t)(b * CC + c)) * SS + qt * 64 + q;
        out[idx] = gm * o + bb * xv[idx];
    }
}

// ---------------------------------------------------------------- launcher
extern "C" void kernel_launch(void* const* d_in, const int* in_sizes, int n_in,
                              void* d_out, int out_size, void* d_ws, size_t ws_size,
                              hipStream_t stream) {
    (void)in_sizes; (void)n_in; (void)out_size; (void)ws_size;

    const size_t TEN = (size_t)4 * SS * CC;          // 2,097,152
    f16* Qt = (f16*)d_ws;                            // 4 MB
    f16* Kt = Qt + TEN;                              // 4 MB
    f16* Vt = Kt + TEN;                              // 4 MB (channel-major)
    f16* Op = Vt + TEN;                              // 2048*8192 f16 = 32 MB
    float* Ml = (float*)(Op + (size_t)2048 * 8192);  // 2048*128 f32 = 1 MB

    PArg aq = { (const float*)d_in[0], (const float*)d_in[3],  (const float*)d_in[4],
                (const float*)d_in[5], (const float*)d_in[6],  (const float*)d_in[7],
                (const float*)d_in[8],  Qt };
    PArg ak = { (const float*)d_in[1], (const float*)d_in[9],  (const float*)d_in[10],
                (const float*)d_in[11], (const float*)d_in[12], (const float*)d_in[13],
                (const float*)d_in[14], Kt };
    PArg av = { (const float*)d_in[2], (const float*)d_in[15], (const float*)d_in[16],
                (const float*)d_in[17], (const float*)d_in[18], (const float*)d_in[19],
                (const float*)d_in[20], Vt };

    hipLaunchKernelGGL(projk, dim3(256, 3), dim3(256), 0, stream, aq, ak, av);
    hipLaunchKernelGGL(attnk, dim3(2048), dim3(256), 0, stream, Qt, Kt, Vt, Op, Ml);
    hipLaunchKernelGGL(mrgk, dim3(1024), dim3(256), 0, stream,
                       Op, Ml, (const float*)d_in[2], (const float*)d_in[21],
                       (const float*)d_in[22], (float*)d_out);
}